// Round 4
// baseline (787.351 us; speedup 1.0000x reference)
//
#include <hip/hip_runtime.h>
#include <float.h>
#include <math.h>

// Problem constants
#define BB 8
#define WW 64
#define NN 128
#define DD 1024
#define PP 512
#define VV 256
#define NBW (BB*WW)           // 512 windows
#define ROWS (NBW*NN)         // 65536 output rows
#define ODIM (DD+VV)          // 1280

// ---------------------------------------------------------------------------
// ws layout (bytes)
#define OFF_FLAG 0
#define OFF_SN   1024                         // [512][1024] f32 = 2 MiB
#define OFF_POS  (OFF_SN + NBW*DD*4)          // [128][512] f32 = 256 KiB
#define OFF_WE   (OFF_POS + NN*PP*4)          // [512][512] f32 = 1 MiB
#define OFF_Q    (OFF_WE + NBW*PP*4)          // [512][512] f32 = 1 MiB
#define OFF_KQ   (OFF_Q + NBW*PP*4)           // [512][1024] f32 = 2 MiB
#define OFF_XA   (OFF_KQ + NBW*DD*4)          // [512][1024] f32 = 2 MiB
#define OFF_OUT  (OFF_XA + NBW*DD*4)          // [512][256] f32 = 512 KiB

// ---------------------------------------------------------------------------
// Detect whether mask arrived as 1-byte bools or int32. Reads only the first
// 64 bytes (safe either way). Any word value > 1 => byte-packed bools.
__global__ void detect_mask_kernel(const unsigned int* __restrict__ mask,
                                   int* __restrict__ flag) {
    if (threadIdx.x == 0) {
        int f = 0;
        for (int i = 0; i < 16; ++i) if (mask[i] > 1u) f = 1;
        *flag = f;
    }
}

__device__ __forceinline__ int load_mask(const void* mask, int flag, int idx) {
    if (flag) return ((const unsigned char*)mask)[idx] ? 1 : 0;
    return ((const int*)mask)[idx] ? 1 : 0;
}

// ---------------------------------------------------------------------------
// Kernel A: per-window masked sum over n, normalized by length -> SN[bw][d]
__global__ __launch_bounds__(256) void sum_kernel(
        const float* __restrict__ x, const void* __restrict__ mask,
        const int* __restrict__ flag, float* __restrict__ SN) {
    __shared__ int m[NN];
    __shared__ float s_inv;
    const int bw = blockIdx.x;
    const int t = threadIdx.x;
    const int f = *flag;
    if (t < NN) m[t] = load_mask(mask, f, bw*NN + t);
    __syncthreads();
    if (t == 0) {
        int cnt = 0;
        for (int n = 0; n < NN; ++n) cnt += 1 - m[n];
        s_inv = 1.0f / (cnt > 0 ? (float)cnt : 1.0f);
    }
    __syncthreads();
    const float4* x4 = (const float4*)(x + (size_t)bw * (NN*DD));
    float4 acc = make_float4(0.f, 0.f, 0.f, 0.f);
    for (int n = 0; n < NN; ++n) {
        if (!m[n]) {
            float4 v = x4[n*(DD/4) + t];
            acc.x += v.x; acc.y += v.y; acc.z += v.z; acc.w += v.w;
        }
    }
    const float iv = s_inv;
    float4 o = make_float4(acc.x*iv, acc.y*iv, acc.z*iv, acc.w*iv);
    ((float4*)(SN + (size_t)bw*DD))[t] = o;
}

// ---------------------------------------------------------------------------
// Positional embedding table: POS[n][j], j<256: sin(n*invf[j]), j>=256: cos
__global__ __launch_bounds__(256) void pos_kernel(
        const float* __restrict__ scale, float* __restrict__ POS) {
    int idx = blockIdx.x*256 + threadIdx.x;
    if (idx >= NN*PP) return;
    int n = idx / PP, j = idx % PP;
    int jj = (j < PP/2) ? j : j - PP/2;
    float inv = powf(10000.0f, -(float)jj / (float)(PP/2));
    float a = (float)n * inv;
    float v = (j < PP/2) ? sinf(a) : cosf(a);
    POS[idx] = v * scale[0];
}

// ---------------------------------------------------------------------------
// Generic fp32 tiled GEMM: C[M,N] = op(A[M,K] @ B)   (B is [K,N], or [N,K] if
// TRANSB). BM=BN=64, BK=16, 256 threads, 4x4 register tile. M,N,K multiples
// of 64/64/16 for our shapes -> no bounds checks.
template<int TRANSB, int RELU>
__global__ __launch_bounds__(256) void gemm_kernel(
        const float* __restrict__ A, const float* __restrict__ B,
        float* __restrict__ C, int M, int N, int K) {
    __shared__ float As[16][64];
    __shared__ float Bs[16][64];
    const int bm = blockIdx.y * 64, bn = blockIdx.x * 64;
    const int t = threadIdx.x;
    const int ty = t / 16, tx = t % 16;
    const int am = t / 4;             // row within tile (A and TRANSB-B loads)
    const int ak = (t % 4) * 4;       // k offset within tile
    float acc[4][4] = {};
    for (int k0 = 0; k0 < K; k0 += 16) {
        float4 av = *(const float4*)(A + (size_t)(bm + am)*K + k0 + ak);
        As[ak+0][am] = av.x; As[ak+1][am] = av.y;
        As[ak+2][am] = av.z; As[ak+3][am] = av.w;
        if (TRANSB) {
            float4 bv = *(const float4*)(B + (size_t)(bn + am)*K + k0 + ak);
            Bs[ak+0][am] = bv.x; Bs[ak+1][am] = bv.y;
            Bs[ak+2][am] = bv.z; Bs[ak+3][am] = bv.w;
        } else {
            int bk = t / 16, bn4 = (t % 16) * 4;
            float4 bv = *(const float4*)(B + (size_t)(k0 + bk)*N + bn + bn4);
            *(float4*)&Bs[bk][bn4] = bv;
        }
        __syncthreads();
        #pragma unroll
        for (int k = 0; k < 16; ++k) {
            float a[4], b[4];
            #pragma unroll
            for (int i = 0; i < 4; ++i) a[i] = As[k][ty*4+i];
            #pragma unroll
            for (int j = 0; j < 4; ++j) b[j] = Bs[k][tx*4+j];
            #pragma unroll
            for (int i = 0; i < 4; ++i)
                #pragma unroll
                for (int j = 0; j < 4; ++j)
                    acc[i][j] = fmaf(a[i], b[j], acc[i][j]);
        }
        __syncthreads();
    }
    #pragma unroll
    for (int i = 0; i < 4; ++i) {
        float4 o = make_float4(acc[i][0], acc[i][1], acc[i][2], acc[i][3]);
        if (RELU) {
            o.x = fmaxf(o.x, 0.f); o.y = fmaxf(o.y, 0.f);
            o.z = fmaxf(o.z, 0.f); o.w = fmaxf(o.w, 0.f);
        }
        *(float4*)(C + (size_t)(bm + ty*4 + i)*N + bn + tx*4) = o;
    }
}

// ---------------------------------------------------------------------------
// Kernel C: per-window attention.
//   dots[n] = (x[n]·kq + q·pos[n]) * p^-0.5 ; mask -> -FLT_MAX ; softmax
//   XA[d]   = sum_n attn[n] * x[n][d]
__global__ __launch_bounds__(256) void attn_kernel(
        const float* __restrict__ x, const void* __restrict__ mask,
        const int* __restrict__ flag, const float* __restrict__ KQ,
        const float* __restrict__ Q, const float* __restrict__ POS,
        float* __restrict__ XA) {
    __shared__ float kq[DD];
    __shared__ float qs[PP];
    __shared__ float dots[NN];
    __shared__ int m[NN];
    const int bw = blockIdx.x;
    const int t = threadIdx.x;
    const int f = *flag;
    ((float4*)kq)[t] = ((const float4*)(KQ + (size_t)bw*DD))[t];
    if (t < PP/4) ((float4*)qs)[t] = ((const float4*)(Q + (size_t)bw*PP))[t];
    if (t < NN) m[t] = load_mask(mask, f, bw*NN + t);
    __syncthreads();

    const float4* x4  = (const float4*)(x + (size_t)bw * (NN*DD));
    const float4* kq4 = (const float4*)kq;
    const float4* q4  = (const float4*)qs;
    const float4* pos4 = (const float4*)POS;
    const int g = t >> 4, l = t & 15;      // 16 groups of 16 lanes
    for (int nn = 0; nn < 8; ++nn) {
        const int n = nn*16 + g;
        if (m[n]) continue;                 // masked -> value overwritten later
        float p = 0.f;
        #pragma unroll
        for (int i = 0; i < 16; ++i) {
            float4 xv = x4[n*(DD/4) + l + 16*i];
            float4 kv = kq4[l + 16*i];
            p = fmaf(xv.x, kv.x, p); p = fmaf(xv.y, kv.y, p);
            p = fmaf(xv.z, kv.z, p); p = fmaf(xv.w, kv.w, p);
        }
        #pragma unroll
        for (int i = 0; i < 8; ++i) {
            float4 pv = pos4[n*(PP/4) + l + 16*i];
            float4 qv = q4[l + 16*i];
            p = fmaf(pv.x, qv.x, p); p = fmaf(pv.y, qv.y, p);
            p = fmaf(pv.z, qv.z, p); p = fmaf(pv.w, qv.w, p);
        }
        p += __shfl_xor(p, 1); p += __shfl_xor(p, 2);
        p += __shfl_xor(p, 4); p += __shfl_xor(p, 8);
        if (l == 0) dots[n] = p * 0.044194173824159216f;   // 512^-0.5
    }
    __syncthreads();

    if (t < 64) {   // wave 0: softmax over 128 entries
        float v0 = m[t]    ? -FLT_MAX : dots[t];
        float v1 = m[t+64] ? -FLT_MAX : dots[t+64];
        float mx = fmaxf(v0, v1);
        #pragma unroll
        for (int off = 1; off < 64; off <<= 1) mx = fmaxf(mx, __shfl_xor(mx, off));
        float e0 = expf(v0 - mx), e1 = expf(v1 - mx);
        float s = e0 + e1;
        #pragma unroll
        for (int off = 1; off < 64; off <<= 1) s += __shfl_xor(s, off);
        float inv = 1.0f / s;
        dots[t] = e0 * inv; dots[t+64] = e1 * inv;
    }
    __syncthreads();

    float4 acc = make_float4(0.f, 0.f, 0.f, 0.f);
    for (int n = 0; n < NN; ++n) {
        float a = dots[n];
        if (a != 0.0f) {
            float4 xv = x4[n*(DD/4) + t];
            acc.x = fmaf(a, xv.x, acc.x); acc.y = fmaf(a, xv.y, acc.y);
            acc.z = fmaf(a, xv.z, acc.z); acc.w = fmaf(a, xv.w, acc.w);
        }
    }
    ((float4*)(XA + (size_t)bw*DD))[t] = acc;
}

// ---------------------------------------------------------------------------
// Kernel E: output assembly. Row r of 1280 floats = [x row | shifted OUT row].
// 320 threads: 256 copy x (1 float4 each), 64 write the out-part.
__global__ __launch_bounds__(320) void out_kernel(
        const float* __restrict__ x, const float* __restrict__ OUT,
        const float* __restrict__ bos, float* __restrict__ o) {
    const int row = blockIdx.x;
    const int t = threadIdx.x;
    float* orow = o + (size_t)row * ODIM;
    if (t < DD/4) {
        float4 v = ((const float4*)(x + (size_t)row*DD))[t];
        ((float4*)orow)[t] = v;
    } else {
        const int c2 = (t - DD/4) * 4;      // 0..252
        const int bw = row >> 7;            // row / 128
        const int w = bw & (WW-1);
        float4 v;
        if (w == 0) v = *(const float4*)(bos + c2);
        else        v = *(const float4*)(OUT + (size_t)(bw-1)*VV + c2);
        *(float4*)(orow + DD + c2) = v;
    }
}

// ---------------------------------------------------------------------------
extern "C" void kernel_launch(void* const* d_in, const int* in_sizes, int n_in,
                              void* d_out, int out_size, void* d_ws, size_t ws_size,
                              hipStream_t stream) {
    const float* x      = (const float*)d_in[0];
    const void*  mask   = d_in[1];
    const float* W_in   = (const float*)d_in[2];
    const float* W_q    = (const float*)d_in[3];
    const float* W_k    = (const float*)d_in[4];
    const float* W_v    = (const float*)d_in[5];
    const float* pscale = (const float*)d_in[6];
    const float* bos    = (const float*)d_in[7];
    float* out = (float*)d_out;

    char* ws = (char*)d_ws;
    int*   FLAG = (int*)(ws + OFF_FLAG);
    float* SN   = (float*)(ws + OFF_SN);
    float* POS  = (float*)(ws + OFF_POS);
    float* WE   = (float*)(ws + OFF_WE);
    float* Q    = (float*)(ws + OFF_Q);
    float* KQ   = (float*)(ws + OFF_KQ);
    float* XA   = (float*)(ws + OFF_XA);
    float* OUTP = (float*)(ws + OFF_OUT);

    hipLaunchKernelGGL(detect_mask_kernel, dim3(1), dim3(64), 0, stream,
                       (const unsigned int*)mask, FLAG);
    hipLaunchKernelGGL(sum_kernel, dim3(NBW), dim3(256), 0, stream,
                       x, mask, FLAG, SN);
    hipLaunchKernelGGL(pos_kernel, dim3((NN*PP + 255)/256), dim3(256), 0, stream,
                       pscale, POS);
    // WE = relu(SN @ W_in)            [512,1024]@[1024,512]
    hipLaunchKernelGGL((gemm_kernel<0,1>), dim3(PP/64, NBW/64), dim3(256), 0, stream,
                       SN, W_in, WE, NBW, PP, DD);
    // Q = WE @ W_q                    [512,512]@[512,512]
    hipLaunchKernelGGL((gemm_kernel<0,0>), dim3(PP/64, NBW/64), dim3(256), 0, stream,
                       WE, W_q, Q, NBW, PP, PP);
    // KQ = Q @ W_k^T                  [512,512]@[512,1024]  (W_k is [1024,512])
    hipLaunchKernelGGL((gemm_kernel<1,0>), dim3(DD/64, NBW/64), dim3(256), 0, stream,
                       Q, W_k, KQ, NBW, DD, PP);
    hipLaunchKernelGGL(attn_kernel, dim3(NBW), dim3(256), 0, stream,
                       x, mask, FLAG, KQ, Q, POS, XA);
    // OUT = XA @ W_v                  [512,1024]@[1024,256]
    hipLaunchKernelGGL((gemm_kernel<0,0>), dim3(VV/64, NBW/64), dim3(256), 0, stream,
                       XA, W_v, OUTP, NBW, VV, DD);
    hipLaunchKernelGGL(out_kernel, dim3(ROWS), dim3(320), 0, stream,
                       x, OUTP, bos, out);
}